// Round 8
// baseline (58.592 us; speedup 1.0000x reference)
//
#include <hip/hip_runtime.h>

// AdditiveAttention: B=2,H=8,Q=512,K=512,D=64
//   scores[b,h,q,k] = V_b + sum_d V_w[d]*tanh(q_proj[q,d] + k_proj[k,d])
//
// tanh(x) = 1 - 2/(1+e^{2x});  e^{2(qp+kp)} = eq*gk,
//   eq = exp2(C*qp), gk = exp2(C*kp), C = 2*log2(e)
// term_d = Vw[d]/A_d,  A_d = 1 + eq_d*gk_d
// score  = (Vb + sumVw) - 2*sum_d term_d
//
// 16-way fraction tree: two 8-subtrees -> (num,P) each, rational combine,
// ONE v_rcp per 16 elements.  62 VALU + 1 rcp / 16 elems = 3.875/elem.
// Overflow-safe: log2(P16) needs sum_16 max(0,x_d) > 44 (~9.7 sigma) to hit
// 2^128 -- impossible for this data.

#define BHX 16
#define SEQ 512
#define DDIM 64
#define QT 64
#define KT 64

typedef float f4 __attribute__((ext_vector_type(4)));
typedef float f2 __attribute__((ext_vector_type(2)));

// Both projections in one launch. blocks 0..511: query->eq, 512..1023: keys->gk.
__global__ __launch_bounds__(256) void proj_kernel(
    const float* __restrict__ query, const float* __restrict__ keys,
    const float* __restrict__ Wa_w,  const float* __restrict__ Wa_b,
    const float* __restrict__ Ua_w,  const float* __restrict__ Ua_b,
    float* __restrict__ eq, float* __restrict__ gk)
{
  const int t = threadIdx.x, lane = t & 63, wave = t >> 6;
  const bool is_k = blockIdx.x >= 512;
  const float* __restrict__ X  = is_k ? keys : query;
  const float* __restrict__ W  = is_k ? Ua_w : Wa_w;
  const float* __restrict__ Bv = is_k ? Ua_b : Wa_b;
  float* __restrict__ out      = is_k ? gk : eq;
  const int row0 = (blockIdx.x & 511) * 16;

  float w[64];
  const float4* W4 = (const float4*)(W + lane * DDIM);
#pragma unroll
  for (int i = 0; i < 16; ++i) {
    float4 v = W4[i];
    w[4*i] = v.x; w[4*i+1] = v.y; w[4*i+2] = v.z; w[4*i+3] = v.w;
  }
#pragma unroll
  for (int i = 0; i < 16; ++i)
    asm volatile("" : "+v"(w[4*i]), "+v"(w[4*i+1]), "+v"(w[4*i+2]), "+v"(w[4*i+3]));

  const float C = 2.885390081777926815f;          // 2*log2(e)
  const float b = Bv[lane];

#pragma unroll 1
  for (int i = 0; i < 4; ++i) {
    const int r   = row0 + wave * 4 + i;
    const int off = __builtin_amdgcn_readfirstlane(r * DDIM);
    const float* xr = X + off;                    // wave-uniform -> s_load
    float a0 = 0, a1 = 0, a2 = 0, a3 = 0;
#pragma unroll
    for (int e = 0; e < 64; e += 4) {
      a0 = __builtin_fmaf(xr[e],     w[e],     a0);
      a1 = __builtin_fmaf(xr[e + 1], w[e + 1], a1);
      a2 = __builtin_fmaf(xr[e + 2], w[e + 2], a2);
      a3 = __builtin_fmaf(xr[e + 3], w[e + 3], a3);
    }
    float p = ((a0 + a1) + (a2 + a3)) + b;
    out[(size_t)r * DDIM + lane] = __builtin_amdgcn_exp2f(C * p);
  }
}

// sum_{j=0..7} vw[j]/A[j] as a rational pair (num, P): 29 VALU, no rcp.
__device__ __forceinline__ void tree8(const float* __restrict__ A,
                                      const float* __restrict__ vw,
                                      float& num, float& P)
{
  const float n01 = __builtin_fmaf(vw[1], A[0], vw[0] * A[1]);
  const float n23 = __builtin_fmaf(vw[3], A[2], vw[2] * A[3]);
  const float n45 = __builtin_fmaf(vw[5], A[4], vw[4] * A[5]);
  const float n67 = __builtin_fmaf(vw[7], A[6], vw[6] * A[7]);
  const float P01 = A[0] * A[1], P23 = A[2] * A[3];
  const float P45 = A[4] * A[5], P67 = A[6] * A[7];
  const float n0123 = __builtin_fmaf(n23, P01, n01 * P23);
  const float n4567 = __builtin_fmaf(n67, P45, n45 * P67);
  const float P0123 = P01 * P23, P4567 = P45 * P67;
  num = __builtin_fmaf(n4567, P0123, n0123 * P4567);
  P   = P0123 * P4567;
}

// Grid (8,8,16)=1024 blocks = exactly 4 blocks/CU at 4 waves/SIMD (one full
// resident round, no tail). Block = 64 k (lanes) x 64 q (16 per wave).
__global__ __launch_bounds__(256, 4) void score_kernel(
    const float* __restrict__ eq,   // [BH*512][64]
    const float* __restrict__ gk,   // [BH*512][64]
    const float* __restrict__ Vw,   // [64]
    const float* __restrict__ Vb,   // [1]
    float* __restrict__ out)        // [BH,512,512]
{
  __shared__ float ql[QT * DDIM];   // 16 KB q-tile, read via uniform broadcast

  const int bh   = blockIdx.z;
  const int q0   = blockIdx.y * QT;
  const int k0   = blockIdx.x * KT;
  const int t    = threadIdx.x;
  const int lane = t & 63;
  const int wave = t >> 6;

  // ---- lane's k-row g[0..63] via asm loads (pinned in VGPRs, R5 lesson) ----
  f4 G[16];
  {
    const float* ga = gk + (size_t)(bh * SEQ + k0 + lane) * DDIM;
    asm volatile("global_load_dwordx4 %0, %1, off offset:0"   : "=v"(G[0])  : "v"(ga));
    asm volatile("global_load_dwordx4 %0, %1, off offset:16"  : "=v"(G[1])  : "v"(ga));
    asm volatile("global_load_dwordx4 %0, %1, off offset:32"  : "=v"(G[2])  : "v"(ga));
    asm volatile("global_load_dwordx4 %0, %1, off offset:48"  : "=v"(G[3])  : "v"(ga));
    asm volatile("global_load_dwordx4 %0, %1, off offset:64"  : "=v"(G[4])  : "v"(ga));
    asm volatile("global_load_dwordx4 %0, %1, off offset:80"  : "=v"(G[5])  : "v"(ga));
    asm volatile("global_load_dwordx4 %0, %1, off offset:96"  : "=v"(G[6])  : "v"(ga));
    asm volatile("global_load_dwordx4 %0, %1, off offset:112" : "=v"(G[7])  : "v"(ga));
    asm volatile("global_load_dwordx4 %0, %1, off offset:128" : "=v"(G[8])  : "v"(ga));
    asm volatile("global_load_dwordx4 %0, %1, off offset:144" : "=v"(G[9])  : "v"(ga));
    asm volatile("global_load_dwordx4 %0, %1, off offset:160" : "=v"(G[10]) : "v"(ga));
    asm volatile("global_load_dwordx4 %0, %1, off offset:176" : "=v"(G[11]) : "v"(ga));
    asm volatile("global_load_dwordx4 %0, %1, off offset:192" : "=v"(G[12]) : "v"(ga));
    asm volatile("global_load_dwordx4 %0, %1, off offset:208" : "=v"(G[13]) : "v"(ga));
    asm volatile("global_load_dwordx4 %0, %1, off offset:224" : "=v"(G[14]) : "v"(ga));
    asm volatile("global_load_dwordx4 %0, %1, off offset:240" : "=v"(G[15]) : "v"(ga));
  }

  // ---- stage 64-row q-tile into LDS (coalesced, 4 float4 per thread) ----
  {
    const float4* src = (const float4*)(eq + (size_t)(bh * SEQ + q0) * DDIM);
    float4* dst = (float4*)ql;
#pragma unroll
    for (int j = 0; j < 4; ++j) dst[t + 256 * j] = src[t + 256 * j];
  }

  // acc0 = V_b + sum_d V_w[d]  (uniform, scalar pipe)
  float acc0 = Vb[0];
#pragma unroll
  for (int d = 0; d < 64; ++d) acc0 += Vw[d];

  __syncthreads();

  asm volatile("s_waitcnt vmcnt(0)"
               : "+v"(G[0]), "+v"(G[1]), "+v"(G[2]),  "+v"(G[3]),
                 "+v"(G[4]), "+v"(G[5]), "+v"(G[6]),  "+v"(G[7]),
                 "+v"(G[8]), "+v"(G[9]), "+v"(G[10]), "+v"(G[11]),
                 "+v"(G[12]),"+v"(G[13]),"+v"(G[14]), "+v"(G[15])
               :: "memory");

  const size_t obase = (size_t)(bh * SEQ + q0 + wave * 16) * SEQ + k0 + lane;

#pragma unroll 1
  for (int qi = 0; qi < 16; ++qi) {
    const f2* ev = (const f2*)(ql + (wave * 16 + qi) * DDIM);
    float accA = 0.f, accB = 0.f;
#pragma unroll
    for (int g = 0; g < 4; ++g) {           // 16 d's per group, 1 rcp each
      float A[16];
#pragma unroll
      for (int j = 0; j < 8; ++j) {         // 8 ds_read_b64 (broadcast)
        const f2 e = ev[8 * g + j];
        A[2*j]     = __builtin_fmaf(e.x, G[4*g + (j >> 1)][(2*j) & 3],     1.0f);
        A[2*j + 1] = __builtin_fmaf(e.y, G[4*g + (j >> 1)][(2*j + 1) & 3], 1.0f);
      }
      float numA, PA, numB, PB;
      tree8(A,     Vw + 16 * g,     numA, PA);
      tree8(A + 8, Vw + 16 * g + 8, numB, PB);
      const float num = __builtin_fmaf(numA, PB, numB * PA);
      const float r   = __builtin_amdgcn_rcpf(PA * PB);
      if (g & 1) accB = __builtin_fmaf(num, r, accB);
      else       accA = __builtin_fmaf(num, r, accA);
    }
    out[obase + (size_t)qi * SEQ] = __builtin_fmaf(-2.f, accA + accB, acc0);
  }
}

extern "C" void kernel_launch(void* const* d_in, const int* in_sizes, int n_in,
                              void* d_out, int out_size, void* d_ws, size_t ws_size,
                              hipStream_t stream) {
  const float* query = (const float*)d_in[0];  // [2,8,512,64]
  const float* keys  = (const float*)d_in[1];  // [2,8,512,64]
  const float* Wa_w  = (const float*)d_in[2];  // [64,64]
  const float* Wa_b  = (const float*)d_in[3];  // [64]
  const float* Ua_w  = (const float*)d_in[4];  // [64,64]
  const float* Ua_b  = (const float*)d_in[5];  // [64]
  const float* V_w   = (const float*)d_in[6];  // [64]
  const float* V_b   = (const float*)d_in[7];  // [1]
  float* out = (float*)d_out;

  const int R = BHX * SEQ;                 // 8192 rows each side
  float* eq = (float*)d_ws;                // 2 MiB
  float* gk = eq + (size_t)R * DDIM;       // 2 MiB

  proj_kernel<<<1024, 256, 0, stream>>>(query, keys, Wa_w, Wa_b,
                                        Ua_w, Ua_b, eq, gk);

  dim3 grid(SEQ / KT, SEQ / QT, BHX);      // (8,8,16) = 1024 blocks
  score_kernel<<<grid, 256, 0, stream>>>(eq, gk, V_w, V_b, out);
}

// Round 9
// 47.719 us; speedup vs baseline: 1.2279x; 1.2279x over previous
//
#include <hip/hip_runtime.h>

// AdditiveAttention: B=2,H=8,Q=512,K=512,D=64
//   scores[b,h,q,k] = V_b + sum_d V_w[d]*tanh(q_proj[q,d] + k_proj[k,d])
//
// tanh(x) = 1 - 2/(1+e^{2x});  e^{2(qp+kp)} = eq*gk,
//   eq = exp2(C*qp), gk = exp2(C*kp), C = 2*log2(e)
// term_d = Vw[d]/A_d,  A_d = 1 + eq_d*gk_d
// score  = (Vb + sumVw) - 2*sum_d term_d
//
// 16-way fraction tree (R7/R8-proven): ONE v_rcp per 16 elements.
//
// R8 lesson: asm-pinning 64+ values forces SPILLS (VGPR=64 reported vs >=80
// pinned; WRITE_SIZE 28.7MB vs 16.7MB output = scratch stores). This round:
// no pins, low register pressure by design; k-data lives in LDS transposed
// [d][k] (+1 pad), refreshed 16 regs at a time per d-group.

#define BHX 16
#define SEQ 512
#define DDIM 64
#define QT 32
#define KT 64

typedef float f4 __attribute__((ext_vector_type(4)));

// Both projections in one launch. blocks 0..511: query->eq, 512..1023: keys->gk.
__global__ __launch_bounds__(256) void proj_kernel(
    const float* __restrict__ query, const float* __restrict__ keys,
    const float* __restrict__ Wa_w,  const float* __restrict__ Wa_b,
    const float* __restrict__ Ua_w,  const float* __restrict__ Ua_b,
    float* __restrict__ eq, float* __restrict__ gk)
{
  const int t = threadIdx.x, lane = t & 63, wave = t >> 6;
  const bool is_k = blockIdx.x >= 512;
  const float* __restrict__ X  = is_k ? keys : query;
  const float* __restrict__ W  = is_k ? Ua_w : Wa_w;
  const float* __restrict__ Bv = is_k ? Ua_b : Wa_b;
  float* __restrict__ out      = is_k ? gk : eq;
  const int row0 = (blockIdx.x & 511) * 16;

  float w[64];
  const float4* W4 = (const float4*)(W + lane * DDIM);
#pragma unroll
  for (int i = 0; i < 16; ++i) {
    float4 v = W4[i];
    w[4*i] = v.x; w[4*i+1] = v.y; w[4*i+2] = v.z; w[4*i+3] = v.w;
  }

  const float C = 2.885390081777926815f;          // 2*log2(e)
  const float b = Bv[lane];

#pragma unroll 1
  for (int i = 0; i < 4; ++i) {
    const int r   = row0 + wave * 4 + i;
    const int off = __builtin_amdgcn_readfirstlane(r * DDIM);
    const float* xr = X + off;                    // wave-uniform -> s_load
    float a0 = 0, a1 = 0, a2 = 0, a3 = 0;
#pragma unroll
    for (int e = 0; e < 64; e += 4) {
      a0 = __builtin_fmaf(xr[e],     w[e],     a0);
      a1 = __builtin_fmaf(xr[e + 1], w[e + 1], a1);
      a2 = __builtin_fmaf(xr[e + 2], w[e + 2], a2);
      a3 = __builtin_fmaf(xr[e + 3], w[e + 3], a3);
    }
    float p = ((a0 + a1) + (a2 + a3)) + b;
    out[(size_t)r * DDIM + lane] = __builtin_amdgcn_exp2f(C * p);
  }
}

// sum_{j=0..7} vw[j]/A[j] as a rational pair (num, P): 29 VALU, no rcp.
__device__ __forceinline__ void tree8(const float* __restrict__ A,
                                      const float* __restrict__ vw,
                                      float& num, float& P)
{
  const float n01 = __builtin_fmaf(vw[1], A[0], vw[0] * A[1]);
  const float n23 = __builtin_fmaf(vw[3], A[2], vw[2] * A[3]);
  const float n45 = __builtin_fmaf(vw[5], A[4], vw[4] * A[5]);
  const float n67 = __builtin_fmaf(vw[7], A[6], vw[6] * A[7]);
  const float P01 = A[0] * A[1], P23 = A[2] * A[3];
  const float P45 = A[4] * A[5], P67 = A[6] * A[7];
  const float n0123 = __builtin_fmaf(n23, P01, n01 * P23);
  const float n4567 = __builtin_fmaf(n67, P45, n45 * P67);
  const float P0123 = P01 * P23, P4567 = P45 * P67;
  num = __builtin_fmaf(n4567, P0123, n0123 * P4567);
  P   = P0123 * P4567;
}

// Grid (8,16,16)=2048 blocks. Block = 64 k (lanes) x 32 q (8 per wave).
// LDS: gk transposed [64][65] (16.6KB) + q-tile (8KB) = 24.6KB -> 6 blk/CU.
__global__ __launch_bounds__(256) void score_kernel(
    const float* __restrict__ eq,   // [BH*512][64]
    const float* __restrict__ gk,   // [BH*512][64]
    const float* __restrict__ Vw,   // [64]
    const float* __restrict__ Vb,   // [1]
    float* __restrict__ out)        // [BH,512,512]
{
  __shared__ float gk_l[DDIM][KT + 1];  // [d][k], +1 pad: both sides 2/bank
  __shared__ float ql[QT * DDIM];       // [q][d], read via uniform broadcast

  const int bh   = blockIdx.z;
  const int q0   = blockIdx.y * QT;
  const int k0   = blockIdx.x * KT;
  const int t    = threadIdx.x;
  const int lane = t & 63;
  const int wave = t >> 6;

  // ---- stage gk tile transposed: wave stages k rows wave*16..+15, lane=d ----
  {
    const float* base = gk + (size_t)(bh * SEQ + k0 + wave * 16) * DDIM;
#pragma unroll
    for (int i = 0; i < 16; ++i)
      gk_l[lane][wave * 16 + i] = base[i * DDIM + lane];
  }
  // ---- stage q-tile (coalesced, 2 float4 per thread) ----
  {
    const float4* src = (const float4*)(eq + (size_t)(bh * SEQ + q0) * DDIM);
    float4* dst = (float4*)ql;
    dst[t]       = src[t];
    dst[t + 256] = src[t + 256];
  }

  // acc0 = V_b + sum_d V_w[d]  (uniform, scalar pipe)
  float acc0 = Vb[0];
#pragma unroll
  for (int d = 0; d < 64; ++d) acc0 += Vw[d];

  __syncthreads();

  float acc[8] = {0.f, 0.f, 0.f, 0.f, 0.f, 0.f, 0.f, 0.f};
  const int qrow0 = wave * 8;

#pragma unroll 1
  for (int g = 0; g < 4; ++g) {           // d-groups of 16
    // this lane's 16 k-side values for the group (conflict-free b32 reads)
    float G[16];
#pragma unroll
    for (int j = 0; j < 16; ++j) G[j] = gk_l[16 * g + j][lane];
    // group slice of Vw -> SGPRs
    float vwl[16];
#pragma unroll
    for (int j = 0; j < 16; ++j) vwl[j] = Vw[16 * g + j];

#pragma unroll
    for (int qi = 0; qi < 8; ++qi) {      // fully unrolled: acc[] static
      const f4* ev = (const f4*)(ql + (qrow0 + qi) * DDIM + 16 * g);
      float A[16];
#pragma unroll
      for (int j = 0; j < 4; ++j) {       // 4 broadcast ds_read_b128
        const f4 e = ev[j];
        A[4*j]     = __builtin_fmaf(e.x, G[4*j],     1.0f);
        A[4*j + 1] = __builtin_fmaf(e.y, G[4*j + 1], 1.0f);
        A[4*j + 2] = __builtin_fmaf(e.z, G[4*j + 2], 1.0f);
        A[4*j + 3] = __builtin_fmaf(e.w, G[4*j + 3], 1.0f);
      }
      float numA, PA, numB, PB;
      tree8(A,     vwl,     numA, PA);
      tree8(A + 8, vwl + 8, numB, PB);
      const float num = __builtin_fmaf(numA, PB, numB * PA);
      acc[qi] = __builtin_fmaf(num, __builtin_amdgcn_rcpf(PA * PB), acc[qi]);
    }
  }

  const size_t obase = (size_t)(bh * SEQ + q0 + qrow0) * SEQ + k0 + lane;
#pragma unroll
  for (int qi = 0; qi < 8; ++qi)
    out[obase + (size_t)qi * SEQ] = __builtin_fmaf(-2.f, acc[qi], acc0);
}

extern "C" void kernel_launch(void* const* d_in, const int* in_sizes, int n_in,
                              void* d_out, int out_size, void* d_ws, size_t ws_size,
                              hipStream_t stream) {
  const float* query = (const float*)d_in[0];  // [2,8,512,64]
  const float* keys  = (const float*)d_in[1];  // [2,8,512,64]
  const float* Wa_w  = (const float*)d_in[2];  // [64,64]
  const float* Wa_b  = (const float*)d_in[3];  // [64]
  const float* Ua_w  = (const float*)d_in[4];  // [64,64]
  const float* Ua_b  = (const float*)d_in[5];  // [64]
  const float* V_w   = (const float*)d_in[6];  // [64]
  const float* V_b   = (const float*)d_in[7];  // [1]
  float* out = (float*)d_out;

  const int R = BHX * SEQ;                 // 8192 rows each side
  float* eq = (float*)d_ws;                // 2 MiB
  float* gk = eq + (size_t)R * DDIM;       // 2 MiB

  proj_kernel<<<1024, 256, 0, stream>>>(query, keys, Wa_w, Wa_b,
                                        Ua_w, Ua_b, eq, gk);

  dim3 grid(SEQ / KT, SEQ / QT, BHX);      // (8,16,16) = 2048 blocks
  score_kernel<<<grid, 256, 0, stream>>>(eq, gk, V_w, V_b, out);
}

// Round 10
// 47.672 us; speedup vs baseline: 1.2291x; 1.0010x over previous
//
#include <hip/hip_runtime.h>

// AdditiveAttention: B=2,H=8,Q=512,K=512,D=64
//   scores[b,h,q,k] = V_b + sum_d V_w[d]*tanh(q_proj[q,d] + k_proj[k,d])
//
// tanh(x) = 1 - 2/(1+e^{2x});  e^{2(qp+kp)} = eq*gk,
//   eq = exp2(C*qp), gk = exp2(C*kp), C = 2*log2(e)
// term_d = Vw[d]/A_d,  A_d = 1 + eq_d*gk_d
// score  = (Vb + sumVw) - 2*sum_d term_d
//
// 16-way fraction tree (R7/R8-proven): ONE v_rcp per 16 elements.
// R8 lesson: no asm pins (they forced spills). R10 change: depth-2 register
// double-buffer on the broadcast e-loads so ds_read latency hides under the
// previous iteration's 63-VALU tree (R9 stall theory: lgkm latency exposed
// per (g,qi) body).

#define BHX 16
#define SEQ 512
#define DDIM 64
#define QT 32
#define KT 64

typedef float f4 __attribute__((ext_vector_type(4)));

// Both projections in one launch. blocks 0..511: query->eq, 512..1023: keys->gk.
__global__ __launch_bounds__(256) void proj_kernel(
    const float* __restrict__ query, const float* __restrict__ keys,
    const float* __restrict__ Wa_w,  const float* __restrict__ Wa_b,
    const float* __restrict__ Ua_w,  const float* __restrict__ Ua_b,
    float* __restrict__ eq, float* __restrict__ gk)
{
  const int t = threadIdx.x, lane = t & 63, wave = t >> 6;
  const bool is_k = blockIdx.x >= 512;
  const float* __restrict__ X  = is_k ? keys : query;
  const float* __restrict__ W  = is_k ? Ua_w : Wa_w;
  const float* __restrict__ Bv = is_k ? Ua_b : Wa_b;
  float* __restrict__ out      = is_k ? gk : eq;
  const int row0 = (blockIdx.x & 511) * 16;

  float w[64];
  const float4* W4 = (const float4*)(W + lane * DDIM);
#pragma unroll
  for (int i = 0; i < 16; ++i) {
    float4 v = W4[i];
    w[4*i] = v.x; w[4*i+1] = v.y; w[4*i+2] = v.z; w[4*i+3] = v.w;
  }

  const float C = 2.885390081777926815f;          // 2*log2(e)
  const float b = Bv[lane];

#pragma unroll 1
  for (int i = 0; i < 4; ++i) {
    const int r   = row0 + wave * 4 + i;
    const int off = __builtin_amdgcn_readfirstlane(r * DDIM);
    const float* xr = X + off;                    // wave-uniform -> s_load
    float a0 = 0, a1 = 0, a2 = 0, a3 = 0;
#pragma unroll
    for (int e = 0; e < 64; e += 4) {
      a0 = __builtin_fmaf(xr[e],     w[e],     a0);
      a1 = __builtin_fmaf(xr[e + 1], w[e + 1], a1);
      a2 = __builtin_fmaf(xr[e + 2], w[e + 2], a2);
      a3 = __builtin_fmaf(xr[e + 3], w[e + 3], a3);
    }
    float p = ((a0 + a1) + (a2 + a3)) + b;
    out[(size_t)r * DDIM + lane] = __builtin_amdgcn_exp2f(C * p);
  }
}

// sum_{j=0..7} vw[j]/A[j] as a rational pair (num, P): no rcp.
__device__ __forceinline__ void tree8(const float* __restrict__ A,
                                      const float* __restrict__ vw,
                                      float& num, float& P)
{
  const float n01 = __builtin_fmaf(vw[1], A[0], vw[0] * A[1]);
  const float n23 = __builtin_fmaf(vw[3], A[2], vw[2] * A[3]);
  const float n45 = __builtin_fmaf(vw[5], A[4], vw[4] * A[5]);
  const float n67 = __builtin_fmaf(vw[7], A[6], vw[6] * A[7]);
  const float P01 = A[0] * A[1], P23 = A[2] * A[3];
  const float P45 = A[4] * A[5], P67 = A[6] * A[7];
  const float n0123 = __builtin_fmaf(n23, P01, n01 * P23);
  const float n4567 = __builtin_fmaf(n67, P45, n45 * P67);
  const float P0123 = P01 * P23, P4567 = P45 * P67;
  num = __builtin_fmaf(n4567, P0123, n0123 * P4567);
  P   = P0123 * P4567;
}

// Grid (8,16,16)=2048 blocks. Block = 64 k (lanes) x 32 q (8 per wave).
// LDS: gk transposed [64][65] (16.6KB) + q-tile (8KB) = 24.6KB -> 6 blk/CU.
__global__ __launch_bounds__(256) void score_kernel(
    const float* __restrict__ eq,   // [BH*512][64]
    const float* __restrict__ gk,   // [BH*512][64]
    const float* __restrict__ Vw,   // [64]
    const float* __restrict__ Vb,   // [1]
    float* __restrict__ out)        // [BH,512,512]
{
  __shared__ float gk_l[DDIM][KT + 1];  // [d][k], +1 pad: both sides 2/bank
  __shared__ float ql[QT * DDIM];       // [q][d], read via uniform broadcast

  const int bh   = blockIdx.z;
  const int q0   = blockIdx.y * QT;
  const int k0   = blockIdx.x * KT;
  const int t    = threadIdx.x;
  const int lane = t & 63;
  const int wave = t >> 6;

  // ---- stage gk tile transposed: wave stages k rows wave*16..+15, lane=d ----
  {
    const float* base = gk + (size_t)(bh * SEQ + k0 + wave * 16) * DDIM;
#pragma unroll
    for (int i = 0; i < 16; ++i)
      gk_l[lane][wave * 16 + i] = base[i * DDIM + lane];
  }
  // ---- stage q-tile (coalesced, 2 float4 per thread) ----
  {
    const float4* src = (const float4*)(eq + (size_t)(bh * SEQ + q0) * DDIM);
    float4* dst = (float4*)ql;
    dst[t]       = src[t];
    dst[t + 256] = src[t + 256];
  }

  // acc0 = V_b + sum_d V_w[d]  (uniform, scalar pipe)
  float acc0 = Vb[0];
#pragma unroll
  for (int d = 0; d < 64; ++d) acc0 += Vw[d];

  __syncthreads();

  float acc[8] = {0.f, 0.f, 0.f, 0.f, 0.f, 0.f, 0.f, 0.f};
  const int qrow0 = wave * 8;

#pragma unroll 1
  for (int g = 0; g < 4; ++g) {           // d-groups of 16
    // this lane's 16 k-side values for the group (conflict-free b32 reads)
    float G[16];
#pragma unroll
    for (int j = 0; j < 16; ++j) G[j] = gk_l[16 * g + j][lane];
    // group slice of Vw (uniform, K$-cached)
    float vwl[16];
#pragma unroll
    for (int j = 0; j < 16; ++j) vwl[j] = Vw[16 * g + j];

    const float* evb = ql + qrow0 * DDIM + 16 * g;
    // depth-2 pipeline: current e-quads in c*, next iteration's in n*
    f4 c0 = *(const f4*)(evb);
    f4 c1 = *(const f4*)(evb + 4);
    f4 c2 = *(const f4*)(evb + 8);
    f4 c3 = *(const f4*)(evb + 12);

#pragma unroll
    for (int qi = 0; qi < 8; ++qi) {      // fully unrolled: all static
      f4 n0 = c0, n1 = c1, n2 = c2, n3 = c3;
      if (qi < 7) {                       // issue next loads BEFORE compute
        const float* p = evb + (qi + 1) * DDIM;
        n0 = *(const f4*)(p);
        n1 = *(const f4*)(p + 4);
        n2 = *(const f4*)(p + 8);
        n3 = *(const f4*)(p + 12);
      }
      float A[16];
      A[0]  = __builtin_fmaf(c0.x, G[0],  1.0f);
      A[1]  = __builtin_fmaf(c0.y, G[1],  1.0f);
      A[2]  = __builtin_fmaf(c0.z, G[2],  1.0f);
      A[3]  = __builtin_fmaf(c0.w, G[3],  1.0f);
      A[4]  = __builtin_fmaf(c1.x, G[4],  1.0f);
      A[5]  = __builtin_fmaf(c1.y, G[5],  1.0f);
      A[6]  = __builtin_fmaf(c1.z, G[6],  1.0f);
      A[7]  = __builtin_fmaf(c1.w, G[7],  1.0f);
      A[8]  = __builtin_fmaf(c2.x, G[8],  1.0f);
      A[9]  = __builtin_fmaf(c2.y, G[9],  1.0f);
      A[10] = __builtin_fmaf(c2.z, G[10], 1.0f);
      A[11] = __builtin_fmaf(c2.w, G[11], 1.0f);
      A[12] = __builtin_fmaf(c3.x, G[12], 1.0f);
      A[13] = __builtin_fmaf(c3.y, G[13], 1.0f);
      A[14] = __builtin_fmaf(c3.z, G[14], 1.0f);
      A[15] = __builtin_fmaf(c3.w, G[15], 1.0f);

      float numA, PA, numB, PB;
      tree8(A,     vwl,     numA, PA);
      tree8(A + 8, vwl + 8, numB, PB);
      const float num = __builtin_fmaf(numA, PB, numB * PA);
      acc[qi] = __builtin_fmaf(num, __builtin_amdgcn_rcpf(PA * PB), acc[qi]);

      c0 = n0; c1 = n1; c2 = n2; c3 = n3;   // static renames (SSA)
    }
  }

  const size_t obase = (size_t)(bh * SEQ + q0 + qrow0) * SEQ + k0 + lane;
#pragma unroll
  for (int qi = 0; qi < 8; ++qi)
    out[obase + (size_t)qi * SEQ] = __builtin_fmaf(-2.f, acc[qi], acc0);
}

extern "C" void kernel_launch(void* const* d_in, const int* in_sizes, int n_in,
                              void* d_out, int out_size, void* d_ws, size_t ws_size,
                              hipStream_t stream) {
  const float* query = (const float*)d_in[0];  // [2,8,512,64]
  const float* keys  = (const float*)d_in[1];  // [2,8,512,64]
  const float* Wa_w  = (const float*)d_in[2];  // [64,64]
  const float* Wa_b  = (const float*)d_in[3];  // [64]
  const float* Ua_w  = (const float*)d_in[4];  // [64,64]
  const float* Ua_b  = (const float*)d_in[5];  // [64]
  const float* V_w   = (const float*)d_in[6];  // [64]
  const float* V_b   = (const float*)d_in[7];  // [1]
  float* out = (float*)d_out;

  const int R = BHX * SEQ;                 // 8192 rows each side
  float* eq = (float*)d_ws;                // 2 MiB
  float* gk = eq + (size_t)R * DDIM;       // 2 MiB

  proj_kernel<<<1024, 256, 0, stream>>>(query, keys, Wa_w, Wa_b,
                                        Ua_w, Ua_b, eq, gk);

  dim3 grid(SEQ / KT, SEQ / QT, BHX);      // (8,16,16) = 2048 blocks
  score_kernel<<<grid, 256, 0, stream>>>(eq, gk, V_w, V_b, out);
}

// Round 12
// 42.168 us; speedup vs baseline: 1.3895x; 1.1305x over previous
//
#include <hip/hip_runtime.h>

// AdditiveAttention: B=2,H=8,Q=512,K=512,D=64
//   scores[b,h,q,k] = V_b + sum_d V_w[d]*tanh(q_proj[q,d] + k_proj[k,d])
//
// tanh(x) = 1 - 2/(1+e^{2x});  e^{2(qp+kp)} = eq*gk,
//   eq = exp2(C*qp), gk = exp2(C*kp), C = 2*log2(e)
// term_d = Vw[d]/A_d,  A_d = 1 + eq_d*gk_d;  score = (Vb+sumVw) - 2*sum term_d
//
// Packed-f32 score: d paired with d+32; each f2 slot runs an independent
// 16-leaf fraction tree (v_pk_* ops). R11 NaN lesson: NEVER form the
// 32-product -- per-slot rcp only (P16 >= 1 always, overflow needs ~10.5
// sigma; proven safe R7-R10). 2 v_rcp per 32 elems.

#define BHX 16
#define SEQ 512
#define DDIM 64
#define QT 32
#define KT 64

typedef float f4 __attribute__((ext_vector_type(4)));
typedef float f2 __attribute__((ext_vector_type(2)));

__device__ __forceinline__ f2 pkfma(f2 a, f2 b, f2 c) {
  return __builtin_elementwise_fma(a, b, c);
}

// Both projections in one launch. blocks 0..255: query->eq, 256..511: keys->gk.
// 32 rows/block, 8 rows/wave. lane = output dim d; W row in VGPRs (NO pins,
// R8 spill lesson); X rows via wave-uniform s_loads.
__global__ __launch_bounds__(256) void proj_kernel(
    const float* __restrict__ query, const float* __restrict__ keys,
    const float* __restrict__ Wa_w,  const float* __restrict__ Wa_b,
    const float* __restrict__ Ua_w,  const float* __restrict__ Ua_b,
    float* __restrict__ eq, float* __restrict__ gk)
{
  const int t = threadIdx.x, lane = t & 63, wave = t >> 6;
  const bool is_k = blockIdx.x >= 256;
  const float* __restrict__ X  = is_k ? keys : query;
  const float* __restrict__ W  = is_k ? Ua_w : Wa_w;
  const float* __restrict__ Bv = is_k ? Ua_b : Wa_b;
  float* __restrict__ out      = is_k ? gk : eq;
  const int row0 = (blockIdx.x & 255) * 32;

  float w[64];
  const float4* W4 = (const float4*)(W + lane * DDIM);
#pragma unroll
  for (int i = 0; i < 16; ++i) {
    float4 v = W4[i];
    w[4*i] = v.x; w[4*i+1] = v.y; w[4*i+2] = v.z; w[4*i+3] = v.w;
  }

  const float C = 2.885390081777926815f;          // 2*log2(e)
  const float b = Bv[lane];

#pragma unroll 1
  for (int i = 0; i < 8; ++i) {
    const int r   = row0 + wave * 8 + i;
    const int off = __builtin_amdgcn_readfirstlane(r * DDIM);
    const float* xr = X + off;                    // wave-uniform -> s_load
    float a0 = 0, a1 = 0, a2 = 0, a3 = 0;
#pragma unroll
    for (int e = 0; e < 64; e += 4) {
      a0 = __builtin_fmaf(xr[e],     w[e],     a0);
      a1 = __builtin_fmaf(xr[e + 1], w[e + 1], a1);
      a2 = __builtin_fmaf(xr[e + 2], w[e + 2], a2);
      a3 = __builtin_fmaf(xr[e + 3], w[e + 3], a3);
    }
    float p = ((a0 + a1) + (a2 + a3)) + b;
    out[(size_t)r * DDIM + lane] = __builtin_amdgcn_exp2f(C * p);
  }
}

// Grid (8,16,16)=2048 blocks. Block = 64 k (lanes) x 32 q (8 per wave).
// LDS layouts interleave d with d+32 so f2 loads give (slot0: d, slot1: d+32).
//   ql  [q][pos(d)]        pos(d) = d<32 ? 2d : 2(d-32)+1     (8 KB)
//   gkl [j][2k + (d>=32)]  j = d&31, f2 read at [j][2*lane]    (16.6 KB)
__global__ __launch_bounds__(256) void score_kernel(
    const float* __restrict__ eq,   // [BH*512][64]
    const float* __restrict__ gk,   // [BH*512][64]
    const float* __restrict__ Vw,   // [64]
    const float* __restrict__ Vb,   // [1]
    float* __restrict__ out)        // [BH,512,512]
{
  __shared__ float gkl[32][2 * KT + 2];  // f2-aligned rows, +2 pad
  __shared__ float ql[QT * DDIM];

  const int bh   = blockIdx.z;
  const int q0   = blockIdx.y * QT;
  const int k0   = blockIdx.x * KT;
  const int t    = threadIdx.x;
  const int lane = t & 63;
  const int wave = t >> 6;

  // ---- stage gk tile: wave w stages k rows w*16..w*16+15; lane = d ----
  {
    const float* base = gk + (size_t)(bh * SEQ + k0 + wave * 16) * DDIM;
    const int j  = lane & 31;
    const int hi = lane >> 5;            // 0: d<32 slot, 1: d>=32 slot
#pragma unroll
    for (int i = 0; i < 16; ++i) {
      const int k = wave * 16 + i;
      gkl[j][2 * k + hi] = base[i * DDIM + lane];
    }
  }
  // ---- stage q-tile interleaved (each thread: 2 f4 reads, 8 b32 writes) ----
  {
    const float4* src = (const float4*)(eq + (size_t)(bh * SEQ + q0) * DDIM);
#pragma unroll
    for (int half = 0; half < 2; ++half) {
      const float4 v = src[t + 256 * half];
      const int q  = (t >> 4) + 16 * half;
      const int d0 = (t & 15) * 4;
      float* row = ql + q * DDIM;
      const int p0 = (d0 < 32) ? 2 * d0 : 2 * (d0 - 32) + 1;
      row[p0]     = v.x;                 // d0..d0+3 same side of 32
      row[p0 + 2] = v.y;
      row[p0 + 4] = v.z;
      row[p0 + 6] = v.w;
    }
  }

  // acc0 = V_b + sum_d V_w[d]  (uniform)
  float acc0 = Vb[0];
#pragma unroll
  for (int d = 0; d < 64; ++d) acc0 += Vw[d];

  __syncthreads();

  f2 acc2[8];
#pragma unroll
  for (int qi = 0; qi < 8; ++qi) acc2[qi] = f2{0.f, 0.f};
  const int qrow0 = wave * 8;
  const f2 one2 = {1.0f, 1.0f};

#pragma unroll 1
  for (int g = 0; g < 2; ++g) {          // pair-groups: j in [16g, 16g+16)
    // lane's 16 k-side f2 pairs for this group (b64, stride-8B: conflict-free)
    f2 Gp[16];
#pragma unroll
    for (int j = 0; j < 16; ++j)
      Gp[j] = *(const f2*)&gkl[16 * g + j][2 * lane];
    // uniform Vw pairs
    f2 vwp[16];
#pragma unroll
    for (int j = 0; j < 16; ++j)
      vwp[j] = f2{Vw[16 * g + j], Vw[16 * g + j + 32]};

#pragma unroll
    for (int qi = 0; qi < 8; ++qi) {     // fully unrolled: all reg idx static
      const f4* ev = (const f4*)(ql + (qrow0 + qi) * DDIM + 32 * g);
      // 16 f2 leaves: A = pk_fma(e, G, 1)
      f2 A[16];
#pragma unroll
      for (int u = 0; u < 8; ++u) {      // 8 broadcast ds_read_b128
        const f4 e = ev[u];
        A[2*u]     = pkfma(f2{e.x, e.y}, Gp[2*u],     one2);
        A[2*u + 1] = pkfma(f2{e.z, e.w}, Gp[2*u + 1], one2);
      }
      // 16-leaf fraction tree per slot (all vertical pk ops)
      f2 n1[8], P1[8];
#pragma unroll
      for (int u = 0; u < 8; ++u) {
        n1[u] = pkfma(vwp[2*u + 1], A[2*u], vwp[2*u] * A[2*u + 1]);
        P1[u] = A[2*u] * A[2*u + 1];
      }
      f2 n2[4], P2[4];
#pragma unroll
      for (int u = 0; u < 4; ++u) {
        n2[u] = pkfma(n1[2*u + 1], P1[2*u], n1[2*u] * P1[2*u + 1]);
        P2[u] = P1[2*u] * P1[2*u + 1];
      }
      f2 n3[2], P3[2];
#pragma unroll
      for (int u = 0; u < 2; ++u) {
        n3[u] = pkfma(n2[2*u + 1], P2[2*u], n2[2*u] * P2[2*u + 1]);
        P3[u] = P2[2*u] * P2[2*u + 1];
      }
      const f2 n4 = pkfma(n3[1], P3[0], n3[0] * P3[1]);
      const f2 P4 = P3[0] * P3[1];       // product of 16 per slot: >= 1, safe
      // per-slot rcp -- NO 32-product (R11 NaN fix)
      f2 r2;
      r2.x = __builtin_amdgcn_rcpf(P4.x);
      r2.y = __builtin_amdgcn_rcpf(P4.y);
      acc2[qi] = pkfma(n4, r2, acc2[qi]);
    }
  }

  const size_t obase = (size_t)(bh * SEQ + q0 + qrow0) * SEQ + k0 + lane;
#pragma unroll
  for (int qi = 0; qi < 8; ++qi) {
    const float a = acc2[qi].x + acc2[qi].y;
    out[obase + (size_t)qi * SEQ] = __builtin_fmaf(-2.f, a, acc0);
  }
}

extern "C" void kernel_launch(void* const* d_in, const int* in_sizes, int n_in,
                              void* d_out, int out_size, void* d_ws, size_t ws_size,
                              hipStream_t stream) {
  const float* query = (const float*)d_in[0];  // [2,8,512,64]
  const float* keys  = (const float*)d_in[1];  // [2,8,512,64]
  const float* Wa_w  = (const float*)d_in[2];  // [64,64]
  const float* Wa_b  = (const float*)d_in[3];  // [64]
  const float* Ua_w  = (const float*)d_in[4];  // [64,64]
  const float* Ua_b  = (const float*)d_in[5];  // [64]
  const float* V_w   = (const float*)d_in[6];  // [64]
  const float* V_b   = (const float*)d_in[7];  // [1]
  float* out = (float*)d_out;

  const int R = BHX * SEQ;                 // 8192 rows each side
  float* eq = (float*)d_ws;                // 2 MiB
  float* gk = eq + (size_t)R * DDIM;       // 2 MiB

  proj_kernel<<<512, 256, 0, stream>>>(query, keys, Wa_w, Wa_b,
                                       Ua_w, Ua_b, eq, gk);

  dim3 grid(SEQ / KT, SEQ / QT, BHX);      // (8,16,16) = 2048 blocks
  score_kernel<<<grid, 256, 0, stream>>>(eq, gk, V_w, V_b, out);
}